// Round 5
// baseline (957.054 us; speedup 1.0000x reference)
//
#include <hip/hip_runtime.h>
#include <math.h>

#define TT 2048
#define BB 32
#define EE 512
#define NN 512

// ---------------------------------------------------------------------------
// padding_mask dtype detector: int32 0/1 words stay <=1; byte-bool rows are
// monotonic so any packed word is 0x01000000/0x01010000/0x01010101/... (>1).
__global__ void detect_mask_kernel(const unsigned* __restrict__ pm, int* __restrict__ flag) {
    __shared__ int s[1024];
    const int l = threadIdx.x;
    int bad = 0;
    for (int i = l; i < BB * TT; i += 1024) bad |= (pm[i] > 1u);
    s[l] = bad;
    __syncthreads();
    for (int st = 512; st > 0; st >>= 1) { if (l < st) s[l] |= s[l + st]; __syncthreads(); }
    if (l == 0) *flag = s[0];
}

__device__ __forceinline__ int pad_at(const void* pm, int idx, int isByte) {
    return isByte ? (int)(((const unsigned char*)pm)[idx] != 0)
                  : (int)(((const int*)pm)[idx] != 0);
}

// ---------------------------------------------------------------------------
// padding_start[b] = count of not-pad = lengths[b]
__global__ void compute_ps_kernel(const void* __restrict__ pm, const int* __restrict__ flag,
                                  int* __restrict__ ps) {
    __shared__ int s[256];
    const int b = blockIdx.x, l = threadIdx.x;
    const int isByte = *flag;
    int cnt = 0;
    for (int t = l; t < TT; t += 256) cnt += (pad_at(pm, b * TT + t, isByte) == 0);
    s[l] = cnt;
    __syncthreads();
    for (int st = 128; st > 0; st >>= 1) { if (l < st) s[l] += s[l + st]; __syncthreads(); }
    if (l == 0) ps[b] = s[0];
}

// ---------------------------------------------------------------------------
// Fused fp32 GEMM + relu + dot(v) + sigmoid + mask — scalar-A variant.
// Block = 512 threads = 8 waves; each wave owns 8 rows (wave-uniform ->
// A elements come via s_load into SGPRs, consumed as the SGPR operand of
// v_fma_f32 — zero LDS/VALU cost for A). Lanes partition N=512: lane owns
// cols {lane*4..+3} u {256+lane*4..+3} (perfect 16B/lane LDS stride).
// Per k-step per wave: 2 ds_read_b128 feed 64 FMA-instr.
__global__ __launch_bounds__(512) void gemm_weight_kernel(
    const float* __restrict__ x, const void* __restrict__ pm, const int* __restrict__ flag,
    const float* __restrict__ W, const float* __restrict__ bias,
    const float* __restrict__ v, const float* __restrict__ vb,
    float* __restrict__ weight_bt) {
    __shared__ float Bs[8 * 512];
    const int l = threadIdx.x;
    const int lane = l & 63;
    const int wid = __builtin_amdgcn_readfirstlane(l >> 6);   // wave id 0..7, SGPR
    const size_t rowbase = (size_t)blockIdx.x * 64 + (size_t)wid * 8;
    const float* xr = x + rowbase * EE;                       // wave-uniform pointer

    // per-lane column fragments of bias and v (direct from global, coalesced)
    const float4 bias0 = *(const float4*)&bias[lane * 4];
    const float4 bias1 = *(const float4*)&bias[256 + lane * 4];
    const float4 v0 = *(const float4*)&v[lane * 4];
    const float4 v1 = *(const float4*)&v[256 + lane * 4];

    float acc[8][8];
#pragma unroll
    for (int r = 0; r < 8; ++r)
#pragma unroll
        for (int c = 0; c < 8; ++c) acc[r][c] = 0.f;

    for (int k0 = 0; k0 < EE; k0 += 8) {
        // A scalars: uniform loads -> SGPRs (8 rows x 8 k)
        float av[8][8];
#pragma unroll
        for (int r = 0; r < 8; ++r)
#pragma unroll
            for (int kk = 0; kk < 8; ++kk)
                av[r][kk] = xr[(size_t)r * EE + k0 + kk];
        __syncthreads();
        // stage B: 8 k x 512 n = 1024 float4 by 512 threads
#pragma unroll
        for (int j = 0; j < 2; ++j) {
            const int idx = l + j * 512;
            const int kk = idx >> 7, n4 = idx & 127;
            *(float4*)&Bs[kk * 512 + n4 * 4] = *(const float4*)&W[(size_t)(k0 + kk) * NN + n4 * 4];
        }
        __syncthreads();
#pragma unroll
        for (int kk = 0; kk < 8; ++kk) {
            const float4 b0 = *(const float4*)&Bs[kk * 512 + lane * 4];
            const float4 b1 = *(const float4*)&Bs[kk * 512 + 256 + lane * 4];
#pragma unroll
            for (int r = 0; r < 8; ++r) {
                const float a = av[r][kk];
                acc[r][0] = fmaf(a, b0.x, acc[r][0]);
                acc[r][1] = fmaf(a, b0.y, acc[r][1]);
                acc[r][2] = fmaf(a, b0.z, acc[r][2]);
                acc[r][3] = fmaf(a, b0.w, acc[r][3]);
                acc[r][4] = fmaf(a, b1.x, acc[r][4]);
                acc[r][5] = fmaf(a, b1.y, acc[r][5]);
                acc[r][6] = fmaf(a, b1.z, acc[r][6]);
                acc[r][7] = fmaf(a, b1.w, acc[r][7]);
            }
        }
    }
    // epilogue: relu + dot(v) per lane's 8 cols, butterfly across 64 lanes
    float rsum[8];
#pragma unroll
    for (int r = 0; r < 8; ++r) {
        float s = 0.f;
        s = fmaf(fmaxf(acc[r][0] + bias0.x, 0.f), v0.x, s);
        s = fmaf(fmaxf(acc[r][1] + bias0.y, 0.f), v0.y, s);
        s = fmaf(fmaxf(acc[r][2] + bias0.z, 0.f), v0.z, s);
        s = fmaf(fmaxf(acc[r][3] + bias0.w, 0.f), v0.w, s);
        s = fmaf(fmaxf(acc[r][4] + bias1.x, 0.f), v1.x, s);
        s = fmaf(fmaxf(acc[r][5] + bias1.y, 0.f), v1.y, s);
        s = fmaf(fmaxf(acc[r][6] + bias1.z, 0.f), v1.z, s);
        s = fmaf(fmaxf(acc[r][7] + bias1.w, 0.f), v1.w, s);
        rsum[r] = s;
    }
#pragma unroll
    for (int m = 32; m >= 1; m >>= 1) {
#pragma unroll
        for (int r = 0; r < 8; ++r) rsum[r] += __shfl_xor(rsum[r], m, 64);
    }
    if (lane == 0) {
        const int isByte = *flag;
        const float vbias = *vb;
#pragma unroll
        for (int r = 0; r < 8; ++r) {
            const size_t row = rowbase + r;            // row = t*32 + b
            const int tt = (int)(row >> 5), b = (int)(row & 31);
            const float wg = 1.0f / (1.0f + expf(-(rsum[r] + vbias)));
            weight_bt[(size_t)b * TT + tt] = pad_at(pm, b * TT + tt, isByte) ? 0.f : wg;
        }
    }
}

// ---------------------------------------------------------------------------
// Sequential scalar scan, one block per batch. Weights staged through LDS in
// 512-step chunks; lane 0 runs the serial fp32 recurrence (replicates the
// reference's per-step rounding exactly). Branchless core: record always
// written at recs_s[m], m advanced by the fire predicate; dependent chain is
// ~4 VALU ops/step. qsum reduced in parallel by all lanes.
#define CH 512
#define MAXREC 2080
__global__ __launch_bounds__(64) void cif_scan_kernel(
    const float* __restrict__ weight_bt, const int* __restrict__ ps_arr,
    float* __restrict__ cc_bt, float4* __restrict__ recs,
    int* __restrict__ nfr, float* __restrict__ out_q, float* __restrict__ out_marks) {
    __shared__ float wsm[CH];
    __shared__ float ccs[CH];
    __shared__ float mks[CH];
    __shared__ float4 recs_s[MAXREC];
    __shared__ int m_sh;
    const int b = blockIdx.x, l = threadIdx.x;
    const int ps = ps_arr[b];
    const float* wrow = weight_bt + (size_t)b * TT;

    // persistent scalar state (lane 0's registers survive across chunks)
    float prev_w = 0.f, fc = 0.f;
    int m = 0, t_first = 0;
    float qpart = 0.f;   // per-lane partial of sum(w)

    for (int t0 = 0; t0 < TT; t0 += CH) {
        // stage chunk: 64 lanes x 8 floats = 512
        const float4 la = *(const float4*)&wrow[t0 + l * 8];
        const float4 lb = *(const float4*)&wrow[t0 + l * 8 + 4];
        *(float4*)&wsm[l * 8]     = la;
        *(float4*)&wsm[l * 8 + 4] = lb;
        qpart += la.x + la.y + la.z + la.w + lb.x + lb.y + lb.z + lb.w;
        __syncthreads();
        if (l == 0) {
            for (int i = 0; i < CH; i += 8) {
                const float4 wa = *(const float4*)&wsm[i];
                const float4 wb = *(const float4*)&wsm[i + 4];
                const float wv[8] = {wa.x, wa.y, wa.z, wa.w, wb.x, wb.y, wb.z, wb.w};
#pragma unroll
                for (int u = 0; u < 8; ++u) {
                    const int t = t0 + i + u;
                    const float w = wv[u];
                    fc = (t == 0) ? w : fc;
                    const bool fired = (prev_w + w >= 1.0f);
                    const float remained = 1.0f - prev_w;
                    ccs[i + u] = fired ? remained : w;
                    // always-write record; advance m only on fire
                    recs_s[m] = make_float4(__int_as_float(t_first), __int_as_float(t), fc, 1.0f);
                    float mark = fired ? 1.f : 0.f;
                    if (fired) {
                        ++m;
                        t_first = t;
                        fc = w - remained;
                        prev_w = w - remained;
                    } else {
                        prev_w += w;
                    }
                    if (t == ps && prev_w > 0.6f) {   // w==0 at t==ps -> never also fired
                        recs_s[m] = make_float4(__int_as_float(t_first), __int_as_float(t - 1),
                                                fc, 1.0f / (prev_w + 1e-10f));
                        ++m;
                        mark = 1.f;
                    }
                    mks[i + u] = mark;
                }
            }
            m_sh = m;
        }
        __syncthreads();
        // flush chunk coalesced
        *(float4*)&cc_bt[(size_t)b * TT + t0 + l * 8]     = *(const float4*)&ccs[l * 8];
        *(float4*)&cc_bt[(size_t)b * TT + t0 + l * 8 + 4] = *(const float4*)&ccs[l * 8 + 4];
        *(float4*)&out_marks[(size_t)b * TT + t0 + l * 8]     = *(const float4*)&mks[l * 8];
        *(float4*)&out_marks[(size_t)b * TT + t0 + l * 8 + 4] = *(const float4*)&mks[l * 8 + 4];
        __syncthreads();
    }
    // flush recs coalesced
    const int mtot = m_sh;
    for (int j = l; j < mtot; j += 64) recs[b * TT + j] = recs_s[j];
    // qsum reduction
#pragma unroll
    for (int s = 32; s >= 1; s >>= 1) qpart += __shfl_xor(qpart, s, 64);
    if (l == 0) { out_q[b] = qpart; nfr[b] = mtot; }
}

// ---------------------------------------------------------------------------
// Parallel frame materialization: block (j, b) -> compacted slot j of batch b.
// frame = scale * sum_t coeff(t) * x[t, b, :], short window (typ. 2-4 steps).
__global__ __launch_bounds__(128) void cif_out_kernel(
    const float* __restrict__ x, const float* __restrict__ cc_bt,
    const float4* __restrict__ recs, const int* __restrict__ nfr,
    float* __restrict__ out_cif, float* __restrict__ out_mask) {
    const int j = blockIdx.x, b = blockIdx.y;
    const int l = threadIdx.x;
    const int m = nfr[b];
    float4 acc = make_float4(0.f, 0.f, 0.f, 0.f);
    const size_t obase = ((size_t)b * TT + j) * EE + l * 4;
    if (j < m) {
        const float4 r = recs[b * TT + j];
        const int t0 = __float_as_int(r.x);
        const int t1 = __float_as_int(r.y);
        const float fcoef = r.z, scale = r.w;
        for (int t = t0; t <= t1; ++t) {
            const float coeff = (t == t0) ? fcoef : cc_bt[(size_t)b * TT + t];
            const float4 xv = *(const float4*)&x[((size_t)t * BB + b) * EE + l * 4];
            acc.x = fmaf(coeff, xv.x, acc.x);
            acc.y = fmaf(coeff, xv.y, acc.y);
            acc.z = fmaf(coeff, xv.z, acc.z);
            acc.w = fmaf(coeff, xv.w, acc.w);
        }
        acc.x *= scale; acc.y *= scale; acc.z *= scale; acc.w *= scale;
        if (l == 0) out_mask[b * TT + j] = 1.f;
    } else {
        if (l == 0) out_mask[b * TT + j] = 0.f;
    }
    *(float4*)&out_cif[obase] = acc;
}

// ---------------------------------------------------------------------------
extern "C" void kernel_launch(void* const* d_in, const int* in_sizes, int n_in,
                              void* d_out, int out_size, void* d_ws, size_t ws_size,
                              hipStream_t stream) {
    const float* x    = (const float*)d_in[0];   // (T, B, E)
    const void*  pm   = d_in[1];                 // (B, T) bool -> int32 or bytes (detected)
    const float* W    = (const float*)d_in[2];   // (E, N)
    const float* bias = (const float*)d_in[3];   // (N,)
    const float* v    = (const float*)d_in[4];   // (N, 1)
    const float* vb   = (const float*)d_in[5];   // (1,)

    float* ws        = (float*)d_ws;
    float* weight_bt = ws;                                 // BB*TT
    float* cc_bt     = ws + TT * BB;                       // BB*TT
    float4* recs     = (float4*)(ws + 2 * TT * BB);        // BB*TT float4
    int* nfr         = (int*)(ws + 2 * TT * BB + 4 * BB * TT);
    int* ps          = nfr + BB;
    int* flag        = ps + BB;

    float* out_cif   = (float*)d_out;                     // (B, T, E)
    float* out_mask  = out_cif + (size_t)BB * TT * EE;    // (B, T)
    float* out_q     = out_mask + (size_t)BB * TT;        // (B,)
    float* out_marks = out_q + BB;                        // (B, T)

    detect_mask_kernel<<<1, 1024, 0, stream>>>((const unsigned*)pm, flag);
    compute_ps_kernel<<<BB, 256, 0, stream>>>(pm, flag, ps);
    gemm_weight_kernel<<<TT * BB / 64, 512, 0, stream>>>(x, pm, flag, W, bias, v, vb, weight_bt);
    cif_scan_kernel<<<BB, 64, 0, stream>>>(weight_bt, ps, cc_bt, recs, nfr, out_q, out_marks);
    cif_out_kernel<<<dim3(TT, BB), 128, 0, stream>>>(x, cc_bt, recs, nfr, out_cif, out_mask);
}